// Round 11
// baseline (317.661 us; speedup 1.0000x reference)
//
#include <hip/hip_runtime.h>
#include <math.h>

#define TSEQ 2048
#define DIM  512
#define NB   8
#define BTOT 16384
#define SCALE 0.04419417382415922f

typedef __attribute__((ext_vector_type(8))) _Float16 f16x8;
typedef __attribute__((ext_vector_type(4))) float f32x4;
typedef __attribute__((ext_vector_type(16))) float f32x16;
typedef __attribute__((ext_vector_type(8))) unsigned short u16x8;
typedef __attribute__((ext_vector_type(4))) unsigned short u16x4;
typedef unsigned short ushort_t;

__device__ __forceinline__ unsigned short f2h(float f) {
    _Float16 h = (_Float16)f;
    return __builtin_bit_cast(unsigned short, h);
}
__device__ __forceinline__ float h2f(unsigned short u) {
    return (float)__builtin_bit_cast(_Float16, u);
}

// ---------------------------------------------------------------------------
// P0: gather embedding rows -> f16
// ---------------------------------------------------------------------------
__global__ __launch_bounds__(256) void k_split_embed(const int* __restrict__ x,
                                                     const float* __restrict__ embed,
                                                     ushort_t* __restrict__ Ef) {
    int idx = blockIdx.x * 256 + threadIdx.x;
    int row = idx >> 6;
    int c   = (idx & 63) << 3;
    int tok = x[row];
    const float* src = embed + (size_t)tok * DIM + c;
    float4 v0 = *(const float4*)src;
    float4 v1 = *(const float4*)(src + 4);
    float vv[8] = {v0.x, v0.y, v0.z, v0.w, v1.x, v1.y, v1.z, v1.w};
    u16x8 h;
#pragma unroll
    for (int i = 0; i < 8; ++i) h[i] = f2h(vv[i]);
    *(u16x8*)(Ef + (size_t)row * DIM + c) = h;
}

// ---------------------------------------------------------------------------
// P1: fused small fp32 SGEMMs (512x512x512 each) -> f16 outputs
// ---------------------------------------------------------------------------
__global__ __launch_bounds__(256) void k_wgemm(const float* __restrict__ Wq,
                                               const float* __restrict__ Wk,
                                               const float* __restrict__ lin_w,
                                               const float* __restrict__ Wv,
                                               ushort_t* __restrict__ Gtf,
                                               ushort_t* __restrict__ Mf) {
    __shared__ float As[32][33];
    __shared__ float Bs[32][33];
    int tid = threadIdx.x;
    int seg = blockIdx.z;
    int m0 = blockIdx.x * 32;
    int n0 = blockIdx.y * 32;
    int dr = tid >> 3;
    int c4 = (tid & 7) * 4;
    int tx = tid & 15, ty = tid >> 4;

    const float* Bsrc = seg ? Wv : Wq;
    float acc[2][2] = {{0.f, 0.f}, {0.f, 0.f}};

    for (int k0 = 0; k0 < DIM; k0 += 32) {
        float4 a4, b4;
        if (seg == 0) {
            a4 = *(const float4*)(Wk + (size_t)(k0 + dr) * DIM + m0 + c4);
        } else {
            a4 = *(const float4*)(lin_w + (size_t)(m0 + dr) * DIM + k0 + c4);
        }
        b4 = *(const float4*)(Bsrc + (size_t)(k0 + dr) * DIM + n0 + c4);
        __syncthreads();
        if (seg == 0) {
            *(float4*)&As[dr][c4] = a4;
        } else {
            As[c4 + 0][dr] = a4.x; As[c4 + 1][dr] = a4.y;
            As[c4 + 2][dr] = a4.z; As[c4 + 3][dr] = a4.w;
        }
        *(float4*)&Bs[dr][c4] = b4;
        __syncthreads();
#pragma unroll
        for (int k = 0; k < 32; ++k) {
            float a0 = As[k][ty * 2], a1 = As[k][ty * 2 + 1];
            float b0 = Bs[k][tx * 2], b1 = Bs[k][tx * 2 + 1];
            acc[0][0] = fmaf(a0, b0, acc[0][0]);
            acc[0][1] = fmaf(a0, b1, acc[0][1]);
            acc[1][0] = fmaf(a1, b0, acc[1][0]);
            acc[1][1] = fmaf(a1, b1, acc[1][1]);
        }
    }
#pragma unroll
    for (int i = 0; i < 2; ++i)
#pragma unroll
        for (int j = 0; j < 2; ++j) {
            int row = m0 + ty * 2 + i;
            int col = n0 + tx * 2 + j;
            if (seg == 0) {
                Gtf[(size_t)row * DIM + col] = f2h(acc[i][j] * SCALE);
            } else {
                Mf[(size_t)row * DIM + col] = f2h(acc[i][j]);
            }
        }
}

// ---------------------------------------------------------------------------
// K1: H = E . Gt^T — f16, 256M x 128N tile, 8 waves, BK=32, stride-40 LDS
//   (61440 B dynamic -> 2 blocks/CU), one barrier per K-step (16 steps).
// ---------------------------------------------------------------------------
#define PH_NT 16
#define PH_A_SH (256 * 40)
#define PH_B_SH (128 * 40)
#define PH_BUF_SH (PH_A_SH + PH_B_SH)        // 15360 shorts
#define PH_LDS_BYTES (2 * PH_BUF_SH * 2)     // 61440 bytes

__global__ __launch_bounds__(512, 2) void k_proj_h256(const ushort_t* __restrict__ Ef,
                                                      const ushort_t* __restrict__ Gtf,
                                                      ushort_t* __restrict__ Hf) {
    extern __shared__ ushort_t smw[];
    int tid = threadIdx.x;
    int wg  = blockIdx.x;            // 0..255
    int n0  = (wg & 3) * 128;        // Gt rows (output cols)
    int m0  = (wg >> 2) * 256;       // E rows (output rows)

    // staging: g=0 (256 thr) -> E: one row each, 4 chunks of 8 shorts
    //          g=1 (256 thr) -> Gt: 2 thr/row, 2 chunks each
    int g = tid >> 8;
    int u = tid & 255;
    int srow = g ? (u >> 1) : u;
    int scol = g ? (u & 1) * 16 : 0;
    int nch  = g ? 2 : 4;
    const ushort_t* gsrc = g ? Gtf : Ef;
    int panel0 = g ? n0 : m0;
    const ushort_t* gbase = gsrc + (size_t)(panel0 + srow) * DIM + scol;
    int ldst = (g ? PH_A_SH : 0) + srow * 40 + scol;

    int wave = tid >> 6, lane = tid & 63;
    int wm = wave >> 2, wn = wave & 3;
    int l32 = lane & 31, kh = lane >> 5;
    int aoff[4];
#pragma unroll
    for (int mt = 0; mt < 4; ++mt) aoff[mt] = (wm * 128 + mt * 32 + l32) * 40 + kh * 8;
    int boff = PH_A_SH + (wn * 32 + l32) * 40 + kh * 8;

    f32x16 acc[4];
#pragma unroll
    for (int i = 0; i < 4; ++i)
#pragma unroll
        for (int t = 0; t < 16; ++t) acc[i][t] = 0.f;

    u16x8 st8[4];
#pragma unroll
    for (int c = 0; c < 4; ++c)
        if (c < nch) st8[c] = *(const u16x8*)(gbase + c * 8);
#pragma unroll
    for (int c = 0; c < 4; ++c)
        if (c < nch) *(u16x8*)&smw[ldst + c * 8] = st8[c];
    __syncthreads();

    for (int t = 0; t < PH_NT; ++t) {
        int cur = (t & 1) * PH_BUF_SH;
        if (t + 1 < PH_NT) {
            int k0n = (t + 1) * 32;
#pragma unroll
            for (int c = 0; c < 4; ++c)
                if (c < nch) st8[c] = *(const u16x8*)(gbase + k0n + c * 8);
        }
#pragma unroll
        for (int kc = 0; kc < 2; ++kc) {
            f16x8 fa[4], fb;
#pragma unroll
            for (int mt = 0; mt < 4; ++mt)
                fa[mt] = *(const f16x8*)&smw[cur + aoff[mt] + kc * 16];
            fb = *(const f16x8*)&smw[cur + boff + kc * 16];
#pragma unroll
            for (int mt = 0; mt < 4; ++mt)
                acc[mt] = __builtin_amdgcn_mfma_f32_32x32x16_f16(fa[mt], fb, acc[mt], 0, 0, 0);
        }
        if (t + 1 < PH_NT) {
            int nxt = ((t + 1) & 1) * PH_BUF_SH;
#pragma unroll
            for (int c = 0; c < 4; ++c)
                if (c < nch) *(u16x8*)&smw[nxt + ldst + c * 8] = st8[c];
        }
        __syncthreads();
    }

    int col = n0 + wn * 32 + l32;
#pragma unroll
    for (int mt = 0; mt < 4; ++mt) {
        f32x16 c = acc[mt];
#pragma unroll
        for (int rr = 0; rr < 16; ++rr) {
            int row = m0 + wm * 128 + mt * 32 + (rr & 3) + 8 * (rr >> 2) + 4 * kh;
            Hf[(size_t)row * DIM + col] = f2h(c[rr]);
        }
    }
}

// ---------------------------------------------------------------------------
// K2: VLT[d][t] = sum_f Mf[d][f] * Ef[t][f]  (f16 single-pass), d-major
// ---------------------------------------------------------------------------
__global__ __launch_bounds__(256) void k_proj_vlt(const ushort_t* __restrict__ Mf,
                                                  const ushort_t* __restrict__ Ef,
                                                  ushort_t* __restrict__ VLT) {
    __shared__ ushort_t Ah[128][40], Bh[128][40];
    __shared__ ushort_t Ct[128][132];
    int tid = threadIdx.x;
    int m0 = blockIdx.x * 128;   // d
    int n0 = blockIdx.y * 128;   // t
    int wave = tid >> 6, lane = tid & 63;
    int wm = wave >> 1, wn = wave & 1;
    int q = lane >> 4, l16 = lane & 15;
    int r = tid >> 1, c0 = (tid & 1) << 4;

    const ushort_t* gah = Mf + (size_t)(m0 + r) * DIM + c0;
    const ushort_t* gbh = Ef + (size_t)(n0 + r) * DIM + c0;

    const f32x4 fz = {0.f, 0.f, 0.f, 0.f};
    f32x4 acc[4][4];
#pragma unroll
    for (int i = 0; i < 4; ++i)
#pragma unroll
        for (int j = 0; j < 4; ++j) acc[i][j] = fz;

    for (int k0 = 0; k0 < DIM; k0 += 32) {
        u16x8 a0 = *(const u16x8*)(gah + k0);
        u16x8 a1 = *(const u16x8*)(gah + k0 + 8);
        u16x8 b0 = *(const u16x8*)(gbh + k0);
        u16x8 b1 = *(const u16x8*)(gbh + k0 + 8);
        __syncthreads();
        *(u16x8*)&Ah[r][c0] = a0; *(u16x8*)&Ah[r][c0 + 8] = a1;
        *(u16x8*)&Bh[r][c0] = b0; *(u16x8*)&Bh[r][c0 + 8] = b1;
        __syncthreads();
        f16x8 fa[4], fb[4];
#pragma unroll
        for (int t = 0; t < 4; ++t) {
            int ar = wm * 64 + t * 16 + l16;
            int br = wn * 64 + t * 16 + l16;
            fa[t] = *(const f16x8*)&Ah[ar][q * 8];
            fb[t] = *(const f16x8*)&Bh[br][q * 8];
        }
#pragma unroll
        for (int i = 0; i < 4; ++i)
#pragma unroll
            for (int j = 0; j < 4; ++j)
                acc[i][j] = __builtin_amdgcn_mfma_f32_16x16x32_f16(fa[i], fb[j], acc[i][j], 0, 0, 0);
    }
#pragma unroll
    for (int i = 0; i < 4; ++i)
#pragma unroll
        for (int j = 0; j < 4; ++j) {
            int col = wn * 64 + j * 16 + l16;
            f32x4 c = acc[i][j];
#pragma unroll
            for (int rr = 0; rr < 4; ++rr) {
                int row = wm * 64 + i * 16 + q * 4 + rr;
                Ct[row][col] = f2h(c[rr]);
            }
        }
    __syncthreads();
    int sc  = (tid & 31) * 4;
    int sr0 = tid >> 5;
#pragma unroll
    for (int p = 0; p < 16; ++p) {
        int row = p * 8 + sr0;
        *(u16x4*)(VLT + (size_t)(m0 + row) * BTOT + n0 + sc) = *(const u16x4*)&Ct[row][sc];
    }
}

// ---------------------------------------------------------------------------
// K3: S16 = f16(H . E^T) — f16, 256x256 tile, 8 waves, BK=32, stride-40 LDS
//   (81920 B dynamic -> 2 blocks/CU), one barrier per K-step (16 steps).
// ---------------------------------------------------------------------------
#define SC_NT 16
#define SC_PLANE (256 * 40)
#define SC_BUF_SH (2 * SC_PLANE)           // 20480 shorts
#define SC_LDS_BYTES (2 * SC_BUF_SH * 2)   // 81920 bytes

__global__ __launch_bounds__(512, 2) void k_scores256(const ushort_t* __restrict__ Hf,
                                                      const ushort_t* __restrict__ Ef,
                                                      ushort_t* __restrict__ S16) {
    extern __shared__ ushort_t smw[];
    int tid  = threadIdx.x;
    int wg   = blockIdx.x;          // 0..511
    int b    = wg & 7;              // XCD q -> batch q
    int rank = wg >> 3;             // 0..63 -> 8x8 tile grid in 4x4 sub-blocks
    int st   = rank >> 4;
    int r2   = rank & 15;
    int m0 = ((((st & 1) << 2) | (r2 & 3))) * 256;
    int n0 = ((((st >> 1) << 2) | (r2 >> 2))) * 256;

    // staging: g=0 (256 thr) -> H rows m0.., g=1 -> E rows n0..; one row each,
    // 4 chunks of 8 shorts (row slice = 64 B contiguous)
    int g = tid >> 8;
    int u = tid & 255;
    const ushort_t* gsrc = g ? Ef : Hf;
    int panel0 = g ? n0 : m0;
    const ushort_t* gbase = gsrc + (size_t)(b * TSEQ + panel0 + u) * DIM;
    int ldst = g * SC_PLANE + u * 40;

    int wave = tid >> 6, lane = tid & 63;
    int wm = wave >> 2, wn = wave & 3;
    int l32 = lane & 31, kh = lane >> 5;
    int aoff[4], boff[2];
#pragma unroll
    for (int mt = 0; mt < 4; ++mt) aoff[mt] = (wm * 128 + mt * 32 + l32) * 40 + kh * 8;
#pragma unroll
    for (int nt = 0; nt < 2; ++nt) boff[nt] = SC_PLANE + (wn * 64 + nt * 32 + l32) * 40 + kh * 8;

    f32x16 acc[4][2];
#pragma unroll
    for (int i = 0; i < 4; ++i)
#pragma unroll
        for (int j = 0; j < 2; ++j)
#pragma unroll
            for (int t = 0; t < 16; ++t) acc[i][j][t] = 0.f;

    u16x8 st8[4];
#pragma unroll
    for (int c = 0; c < 4; ++c) st8[c] = *(const u16x8*)(gbase + c * 8);
#pragma unroll
    for (int c = 0; c < 4; ++c) *(u16x8*)&smw[ldst + c * 8] = st8[c];
    __syncthreads();

    for (int t = 0; t < SC_NT; ++t) {
        int cur = (t & 1) * SC_BUF_SH;
        if (t + 1 < SC_NT) {
            int k0n = (t + 1) * 32;
#pragma unroll
            for (int c = 0; c < 4; ++c)
                st8[c] = *(const u16x8*)(gbase + k0n + c * 8);
        }
#pragma unroll
        for (int kc = 0; kc < 2; ++kc) {
            f16x8 fa[4], fb[2];
#pragma unroll
            for (int mt = 0; mt < 4; ++mt)
                fa[mt] = *(const f16x8*)&smw[cur + aoff[mt] + kc * 16];
#pragma unroll
            for (int nt = 0; nt < 2; ++nt)
                fb[nt] = *(const f16x8*)&smw[cur + boff[nt] + kc * 16];
#pragma unroll
            for (int mt = 0; mt < 4; ++mt)
#pragma unroll
                for (int nt = 0; nt < 2; ++nt)
                    acc[mt][nt] = __builtin_amdgcn_mfma_f32_32x32x16_f16(fa[mt], fb[nt], acc[mt][nt], 0, 0, 0);
        }
        if (t + 1 < SC_NT) {
            int nxt = ((t + 1) & 1) * SC_BUF_SH;
#pragma unroll
            for (int c = 0; c < 4; ++c)
                *(u16x8*)&smw[nxt + ldst + c * 8] = st8[c];
        }
        __syncthreads();
    }

    ushort_t* Sout = S16 + (size_t)b * TSEQ * TSEQ;
#pragma unroll
    for (int mt = 0; mt < 4; ++mt)
#pragma unroll
        for (int nt = 0; nt < 2; ++nt) {
            int col = n0 + wn * 64 + nt * 32 + l32;
            f32x16 c = acc[mt][nt];
#pragma unroll
            for (int rr = 0; rr < 16; ++rr) {
                int row = m0 + wm * 128 + mt * 32 + (rr & 3) + 8 * (rr >> 2) + 4 * kh;
                Sout[(size_t)row * TSEQ + col] = f2h(c[rr]);
            }
        }
}

// ---------------------------------------------------------------------------
// K4: softexp on f16 S in place: row max, P = f16(exp(s-m)), linv = 1/sum
// ---------------------------------------------------------------------------
__global__ __launch_bounds__(256) void k_softexp(ushort_t* __restrict__ S16,
                                                 float* __restrict__ linv) {
    int row = blockIdx.x;
    int tid = threadIdx.x;
    ushort_t* r = S16 + (size_t)row * TSEQ;
    u16x8 v8 = *(const u16x8*)(r + tid * 8);
    float vv[8];
#pragma unroll
    for (int i = 0; i < 8; ++i) vv[i] = h2f(v8[i]);
    float mx = vv[0];
#pragma unroll
    for (int i = 1; i < 8; ++i) mx = fmaxf(mx, vv[i]);
#pragma unroll
    for (int off = 32; off > 0; off >>= 1) mx = fmaxf(mx, __shfl_xor(mx, off));
    __shared__ float sm[4];
    __shared__ float sl[4];
    if ((tid & 63) == 0) sm[tid >> 6] = mx;
    __syncthreads();
    mx = fmaxf(fmaxf(sm[0], sm[1]), fmaxf(sm[2], sm[3]));
    float s = 0.f;
    u16x8 p;
#pragma unroll
    for (int i = 0; i < 8; ++i) {
        float e = __expf(vv[i] - mx);
        s += e;
        p[i] = f2h(e);
    }
    *(u16x8*)(r + tid * 8) = p;
#pragma unroll
    for (int off = 32; off > 0; off >>= 1) s += __shfl_xor(s, off);
    if ((tid & 63) == 0) sl[tid >> 6] = s;
    __syncthreads();
    if (tid == 0) linv[row] = 1.f / (sl[0] + sl[1] + sl[2] + sl[3]);
}

// ---------------------------------------------------------------------------
// K5: PV — 256-tile 8-wave template, f16, BK=32, stride-40 LDS
//   (61440 B dynamic -> 2 blocks/CU), 64 K-steps.
// ---------------------------------------------------------------------------
#define PV_NT 64
#define PV_A_SH (256 * 40)
#define PV_B_SH (128 * 40)
#define PV_BUF_SH (PV_A_SH + PV_B_SH)        // 15360 shorts
#define PV_LDS_BYTES (2 * PV_BUF_SH * 2)     // 61440 bytes

__global__ __launch_bounds__(512, 2) void k_pv256(const ushort_t* __restrict__ P16,
                                                  const ushort_t* __restrict__ VLT,
                                                  const float* __restrict__ linv,
                                                  const float* __restrict__ lin_b,
                                                  float* __restrict__ accg) {
    extern __shared__ ushort_t smw[];
    __shared__ float linv_s[256], bias_s[128];
    int tid  = threadIdx.x;
    int wg   = blockIdx.x;           // 0..255
    int b    = wg & 7;               // XCD q -> batch q
    int rank = wg >> 3;              // 0..31
    int m0 = (rank >> 2) * 256;      // i tile (8)
    int n0 = (rank & 3) * 128;       // d tile (4, fastest)
    if (tid < 256) linv_s[tid] = linv[b * TSEQ + m0 + tid];
    else if (tid < 384) bias_s[tid - 256] = lin_b[n0 + tid - 256];

    // staging: A (P) 256 rows x 32 sh -> 2 thr/row, 2 chunks each;
    //          B (VLT) 128 rows x 32 sh -> 4 thr/row, 1 chunk each
    int rowA = tid >> 1, scolA = (tid & 1) * 16;
    int rowB = tid >> 2, scolB = (tid & 3) * 8;
    const ushort_t* gA = P16 + (size_t)(b * TSEQ + m0 + rowA) * TSEQ + scolA;
    const ushort_t* gB = VLT + (size_t)(n0 + rowB) * BTOT + b * TSEQ + scolB;
    int wA0 = rowA * 40 + scolA;
    int wB0 = PV_A_SH + rowB * 40 + scolB;

    int wave = tid >> 6, lane = tid & 63;
    int wm = wave >> 1, wn = wave & 1;
    int l32 = lane & 31, kh = lane >> 5;
    int aoff[2], boff[2];
#pragma unroll
    for (int mt = 0; mt < 2; ++mt) aoff[mt] = (wm * 64 + mt * 32 + l32) * 40 + kh * 8;
#pragma unroll
    for (int nt = 0; nt < 2; ++nt) boff[nt] = PV_A_SH + (wn * 64 + nt * 32 + l32) * 40 + kh * 8;

    f32x16 acc[2][2];
#pragma unroll
    for (int i = 0; i < 2; ++i)
#pragma unroll
        for (int j = 0; j < 2; ++j)
#pragma unroll
            for (int t = 0; t < 16; ++t) acc[i][j][t] = 0.f;

    u16x8 st8[3];
    st8[0] = *(const u16x8*)(gA);
    st8[1] = *(const u16x8*)(gA + 8);
    st8[2] = *(const u16x8*)(gB);
    *(u16x8*)&smw[wA0]     = st8[0];
    *(u16x8*)&smw[wA0 + 8] = st8[1];
    *(u16x8*)&smw[wB0]     = st8[2];
    __syncthreads();

    for (int t = 0; t < PV_NT; ++t) {
        int cur = (t & 1) * PV_BUF_SH;
        if (t + 1 < PV_NT) {
            int k0n = (t + 1) * 32;
            st8[0] = *(const u16x8*)(gA + k0n);
            st8[1] = *(const u16x8*)(gA + k0n + 8);
            st8[2] = *(const u16x8*)(gB + k0n);
        }
#pragma unroll
        for (int kc = 0; kc < 2; ++kc) {
            int ka = kc * 16;
            f16x8 fa[2], fb[2];
#pragma unroll
            for (int mt = 0; mt < 2; ++mt) fa[mt] = *(const f16x8*)&smw[cur + aoff[mt] + ka];
#pragma unroll
            for (int nt = 0; nt < 2; ++nt) fb[nt] = *(const f16x8*)&smw[cur + boff[nt] + ka];
#pragma unroll
            for (int mt = 0; mt < 2; ++mt)
#pragma unroll
                for (int nt = 0; nt < 2; ++nt)
                    acc[mt][nt] = __builtin_amdgcn_mfma_f32_32x32x16_f16(fa[mt], fb[nt], acc[mt][nt], 0, 0, 0);
        }
        if (t + 1 < PV_NT) {
            int nxt = ((t + 1) & 1) * PV_BUF_SH;
            *(u16x8*)&smw[nxt + wA0]     = st8[0];
            *(u16x8*)&smw[nxt + wA0 + 8] = st8[1];
            *(u16x8*)&smw[nxt + wB0]     = st8[2];
        }
        __syncthreads();
    }

    float dsum[2] = {0.f, 0.f};
#pragma unroll
    for (int mt = 0; mt < 2; ++mt)
#pragma unroll
        for (int nt = 0; nt < 2; ++nt) {
            f32x16 c = acc[mt][nt];
            float bias = bias_s[wn * 64 + nt * 32 + l32];
#pragma unroll
            for (int rr = 0; rr < 16; ++rr) {
                int row = wm * 64 + mt * 32 + (rr & 3) + 8 * (rr >> 2) + 4 * kh;
                float v = fmaf(c[rr], linv_s[row], bias);
                dsum[nt] += fmaxf(v, 0.f);
            }
        }
#pragma unroll
    for (int nt = 0; nt < 2; ++nt) {
        float v = dsum[nt];
        v += __shfl_xor(v, 32);
        if (kh == 0) atomicAdd(&accg[b * DIM + n0 + wn * 64 + nt * 32 + l32], v);
    }
}

// ---------------------------------------------------------------------------
// K6: out[b] = sigmoid((accg[b]/T) . clf_w + clf_b)
// ---------------------------------------------------------------------------
__global__ void k_final(const float* __restrict__ accg,
                        const float* __restrict__ clf_w,
                        const float* __restrict__ clf_b,
                        float* __restrict__ out) {
    int tid  = threadIdx.x;
    int b    = tid >> 6;
    int lane = tid & 63;
    float s = 0.f;
    for (int d = lane; d < DIM; d += 64) s = fmaf(accg[b * DIM + d], clf_w[d], s);
#pragma unroll
    for (int off = 32; off > 0; off >>= 1) s += __shfl_xor(s, off);
    if (lane == 0) {
        float z = s * (1.0f / TSEQ) + clf_b[0];
        out[b] = 1.f / (1.f + __expf(-z));
    }
}

// ---------------------------------------------------------------------------
extern "C" void kernel_launch(void* const* d_in, const int* in_sizes, int n_in,
                              void* d_out, int out_size, void* d_ws, size_t ws_size,
                              hipStream_t stream) {
    const int*   x     = (const int*)d_in[0];
    const float* embed = (const float*)d_in[1];
    const float* Wq    = (const float*)d_in[2];
    const float* Wk    = (const float*)d_in[3];
    const float* Wv    = (const float*)d_in[4];
    const float* lin_w = (const float*)d_in[5];
    const float* lin_b = (const float*)d_in[6];
    const float* clf_w = (const float*)d_in[7];
    const float* clf_b = (const float*)d_in[8];
    float* out = (float*)d_out;

    char* wsb = (char*)d_ws;
    ushort_t* S16 = (ushort_t*)wsb;                          // 67 MB f16 scores / P in place
    char* p = wsb + (size_t)NB * TSEQ * TSEQ * 4;
    ushort_t* Ef  = (ushort_t*)p;
    ushort_t* Hf  = Ef  + (size_t)BTOT * DIM;
    ushort_t* VLT = Hf  + (size_t)BTOT * DIM;
    ushort_t* Gtf = VLT + (size_t)DIM * BTOT;
    ushort_t* Mf  = Gtf + (size_t)DIM * DIM;
    float* linv = (float*)(Mf + (size_t)DIM * DIM);
    float* accg = linv + BTOT;

    static bool s_attr_done = false;
    if (!s_attr_done) {
        hipFuncSetAttribute((const void*)k_scores256,
                            hipFuncAttributeMaxDynamicSharedMemorySize, SC_LDS_BYTES);
        hipFuncSetAttribute((const void*)k_proj_h256,
                            hipFuncAttributeMaxDynamicSharedMemorySize, PH_LDS_BYTES);
        hipFuncSetAttribute((const void*)k_pv256,
                            hipFuncAttributeMaxDynamicSharedMemorySize, PV_LDS_BYTES);
        s_attr_done = true;
    }

    hipMemsetAsync(accg, 0, NB * DIM * sizeof(float), stream);
    k_split_embed<<<BTOT * 64 / 256, 256, 0, stream>>>(x, embed, Ef);
    k_wgemm<<<dim3(16, 16, 2), 256, 0, stream>>>(Wq, Wk, lin_w, Wv, Gtf, Mf);
    k_proj_h256<<<256, 512, PH_LDS_BYTES, stream>>>(Ef, Gtf, Hf);
    k_proj_vlt<<<dim3(4, 128), 256, 0, stream>>>(Mf, Ef, VLT);
    k_scores256<<<512, 512, SC_LDS_BYTES, stream>>>(Hf, Ef, S16);
    k_softexp<<<BTOT, 256, 0, stream>>>(S16, linv);
    k_pv256<<<256, 512, PV_LDS_BYTES, stream>>>(S16, VLT, linv, lin_b, accg);
    k_final<<<1, 512, 0, stream>>>(accg, clf_w, clf_b, out);
}

// Round 12
// 275.370 us; speedup vs baseline: 1.1536x; 1.1536x over previous
//
#include <hip/hip_runtime.h>
#include <math.h>

#define TSEQ 2048
#define DIM  512
#define NB   8
#define BTOT 16384
#define SCALE 0.04419417382415922f

typedef __attribute__((ext_vector_type(8))) _Float16 f16x8;
typedef __attribute__((ext_vector_type(4))) float f32x4;
typedef __attribute__((ext_vector_type(16))) float f32x16;
typedef __attribute__((ext_vector_type(8))) unsigned short u16x8;
typedef __attribute__((ext_vector_type(4))) unsigned short u16x4;
typedef unsigned short ushort_t;

__device__ __forceinline__ unsigned short f2h(float f) {
    _Float16 h = (_Float16)f;
    return __builtin_bit_cast(unsigned short, h);
}
__device__ __forceinline__ float h2f(unsigned short u) {
    return (float)__builtin_bit_cast(_Float16, u);
}

// ---------------------------------------------------------------------------
// P0: gather embedding rows -> f16
// ---------------------------------------------------------------------------
__global__ __launch_bounds__(256) void k_split_embed(const int* __restrict__ x,
                                                     const float* __restrict__ embed,
                                                     ushort_t* __restrict__ Ef) {
    int idx = blockIdx.x * 256 + threadIdx.x;
    int row = idx >> 6;
    int c   = (idx & 63) << 3;
    int tok = x[row];
    const float* src = embed + (size_t)tok * DIM + c;
    float4 v0 = *(const float4*)src;
    float4 v1 = *(const float4*)(src + 4);
    float vv[8] = {v0.x, v0.y, v0.z, v0.w, v1.x, v1.y, v1.z, v1.w};
    u16x8 h;
#pragma unroll
    for (int i = 0; i < 8; ++i) h[i] = f2h(vv[i]);
    *(u16x8*)(Ef + (size_t)row * DIM + c) = h;
}

// ---------------------------------------------------------------------------
// P1: fused small fp32 SGEMMs (512x512x512 each) -> f16 outputs
// ---------------------------------------------------------------------------
__global__ __launch_bounds__(256) void k_wgemm(const float* __restrict__ Wq,
                                               const float* __restrict__ Wk,
                                               const float* __restrict__ lin_w,
                                               const float* __restrict__ Wv,
                                               ushort_t* __restrict__ Gtf,
                                               ushort_t* __restrict__ Mf) {
    __shared__ float As[32][33];
    __shared__ float Bs[32][33];
    int tid = threadIdx.x;
    int seg = blockIdx.z;
    int m0 = blockIdx.x * 32;
    int n0 = blockIdx.y * 32;
    int dr = tid >> 3;
    int c4 = (tid & 7) * 4;
    int tx = tid & 15, ty = tid >> 4;

    const float* Bsrc = seg ? Wv : Wq;
    float acc[2][2] = {{0.f, 0.f}, {0.f, 0.f}};

    for (int k0 = 0; k0 < DIM; k0 += 32) {
        float4 a4, b4;
        if (seg == 0) {
            a4 = *(const float4*)(Wk + (size_t)(k0 + dr) * DIM + m0 + c4);
        } else {
            a4 = *(const float4*)(lin_w + (size_t)(m0 + dr) * DIM + k0 + c4);
        }
        b4 = *(const float4*)(Bsrc + (size_t)(k0 + dr) * DIM + n0 + c4);
        __syncthreads();
        if (seg == 0) {
            *(float4*)&As[dr][c4] = a4;
        } else {
            As[c4 + 0][dr] = a4.x; As[c4 + 1][dr] = a4.y;
            As[c4 + 2][dr] = a4.z; As[c4 + 3][dr] = a4.w;
        }
        *(float4*)&Bs[dr][c4] = b4;
        __syncthreads();
#pragma unroll
        for (int k = 0; k < 32; ++k) {
            float a0 = As[k][ty * 2], a1 = As[k][ty * 2 + 1];
            float b0 = Bs[k][tx * 2], b1 = Bs[k][tx * 2 + 1];
            acc[0][0] = fmaf(a0, b0, acc[0][0]);
            acc[0][1] = fmaf(a0, b1, acc[0][1]);
            acc[1][0] = fmaf(a1, b0, acc[1][0]);
            acc[1][1] = fmaf(a1, b1, acc[1][1]);
        }
    }
#pragma unroll
    for (int i = 0; i < 2; ++i)
#pragma unroll
        for (int j = 0; j < 2; ++j) {
            int row = m0 + ty * 2 + i;
            int col = n0 + tx * 2 + j;
            if (seg == 0) {
                Gtf[(size_t)row * DIM + col] = f2h(acc[i][j] * SCALE);
            } else {
                Mf[(size_t)row * DIM + col] = f2h(acc[i][j]);
            }
        }
}

// ---------------------------------------------------------------------------
// K1: H = E . Gt^T  — f16 single-pass, 256M x 128N tile, 8 waves, BK=64,
//   double-buffered [*][72] LDS (110 KB), one barrier per K-step (8 steps).
//   (R10 version — best measured.)
// ---------------------------------------------------------------------------
#define PH_NT 8
#define PH_A_SH (256 * 72)
#define PH_B_SH (128 * 72)
#define PH_BUF_SH (PH_A_SH + PH_B_SH)        // 27648 shorts
#define PH_LDS_BYTES (2 * PH_BUF_SH * 2)     // 110592 bytes

__global__ __launch_bounds__(512, 2) void k_proj_h256(const ushort_t* __restrict__ Ef,
                                                      const ushort_t* __restrict__ Gtf,
                                                      ushort_t* __restrict__ Hf) {
    extern __shared__ ushort_t smw[];
    int tid = threadIdx.x;
    int wg  = blockIdx.x;            // 0..255
    int n0  = (wg & 3) * 128;        // Gt rows (output cols)
    int m0  = (wg >> 2) * 256;       // E rows (output rows)

    // staging: g=0 -> E (256 rows, 8 chunks/thread), g=1 -> Gt (128 rows, 4)
    int g = tid >> 8;
    int u = tid & 255;
    int srow = u >> 3;               // 0..31
    int scol = (u & 7) * 8;          // 0..56 shorts
    const ushort_t* gsrc = g ? Gtf : Ef;
    int panel0 = g ? n0 : m0;
    const ushort_t* gbase = gsrc + (size_t)(panel0 + srow) * DIM + scol;
    int ldst = (g ? PH_A_SH : 0) + srow * 72 + scol;
    int nch = g ? 4 : 8;

    int wave = tid >> 6, lane = tid & 63;
    int wm = wave >> 2, wn = wave & 3;
    int l32 = lane & 31, kh = lane >> 5;
    int aoff[4];
#pragma unroll
    for (int mt = 0; mt < 4; ++mt) aoff[mt] = (wm * 128 + mt * 32 + l32) * 72 + kh * 8;
    int boff = PH_A_SH + (wn * 32 + l32) * 72 + kh * 8;

    f32x16 acc[4];
#pragma unroll
    for (int i = 0; i < 4; ++i)
#pragma unroll
        for (int t = 0; t < 16; ++t) acc[i][t] = 0.f;

    u16x8 st8[8];
#pragma unroll
    for (int c = 0; c < 8; ++c)
        if (c < nch) st8[c] = *(const u16x8*)(gbase + (size_t)(c * 32) * DIM);
#pragma unroll
    for (int c = 0; c < 8; ++c)
        if (c < nch) *(u16x8*)&smw[ldst + (c * 32) * 72] = st8[c];
    __syncthreads();

    for (int t = 0; t < PH_NT; ++t) {
        int cur = (t & 1) * PH_BUF_SH;
        if (t + 1 < PH_NT) {
            int k0n = (t + 1) * 64;
#pragma unroll
            for (int c = 0; c < 8; ++c)
                if (c < nch) st8[c] = *(const u16x8*)(gbase + (size_t)(c * 32) * DIM + k0n);
        }
#pragma unroll
        for (int kc = 0; kc < 4; ++kc) {
            f16x8 fa[4], fb;
#pragma unroll
            for (int mt = 0; mt < 4; ++mt)
                fa[mt] = *(const f16x8*)&smw[cur + aoff[mt] + kc * 16];
            fb = *(const f16x8*)&smw[cur + boff + kc * 16];
#pragma unroll
            for (int mt = 0; mt < 4; ++mt)
                acc[mt] = __builtin_amdgcn_mfma_f32_32x32x16_f16(fa[mt], fb, acc[mt], 0, 0, 0);
        }
        if (t + 1 < PH_NT) {
            int nxt = ((t + 1) & 1) * PH_BUF_SH;
#pragma unroll
            for (int c = 0; c < 8; ++c)
                if (c < nch) *(u16x8*)&smw[nxt + ldst + (c * 32) * 72] = st8[c];
        }
        __syncthreads();
    }

    int col = n0 + wn * 32 + l32;
#pragma unroll
    for (int mt = 0; mt < 4; ++mt) {
        f32x16 c = acc[mt];
#pragma unroll
        for (int rr = 0; rr < 16; ++rr) {
            int row = m0 + wm * 128 + mt * 32 + (rr & 3) + 8 * (rr >> 2) + 4 * kh;
            Hf[(size_t)row * DIM + col] = f2h(c[rr]);
        }
    }
}

// ---------------------------------------------------------------------------
// K2: VLT[d][t] = sum_f Mf[d][f] * Ef[t][f]  (f16 single-pass), d-major
// ---------------------------------------------------------------------------
__global__ __launch_bounds__(256) void k_proj_vlt(const ushort_t* __restrict__ Mf,
                                                  const ushort_t* __restrict__ Ef,
                                                  ushort_t* __restrict__ VLT) {
    __shared__ ushort_t Ah[128][40], Bh[128][40];
    __shared__ ushort_t Ct[128][132];
    int tid = threadIdx.x;
    int m0 = blockIdx.x * 128;   // d
    int n0 = blockIdx.y * 128;   // t
    int wave = tid >> 6, lane = tid & 63;
    int wm = wave >> 1, wn = wave & 1;
    int q = lane >> 4, l16 = lane & 15;
    int r = tid >> 1, c0 = (tid & 1) << 4;

    const ushort_t* gah = Mf + (size_t)(m0 + r) * DIM + c0;
    const ushort_t* gbh = Ef + (size_t)(n0 + r) * DIM + c0;

    const f32x4 fz = {0.f, 0.f, 0.f, 0.f};
    f32x4 acc[4][4];
#pragma unroll
    for (int i = 0; i < 4; ++i)
#pragma unroll
        for (int j = 0; j < 4; ++j) acc[i][j] = fz;

    for (int k0 = 0; k0 < DIM; k0 += 32) {
        u16x8 a0 = *(const u16x8*)(gah + k0);
        u16x8 a1 = *(const u16x8*)(gah + k0 + 8);
        u16x8 b0 = *(const u16x8*)(gbh + k0);
        u16x8 b1 = *(const u16x8*)(gbh + k0 + 8);
        __syncthreads();
        *(u16x8*)&Ah[r][c0] = a0; *(u16x8*)&Ah[r][c0 + 8] = a1;
        *(u16x8*)&Bh[r][c0] = b0; *(u16x8*)&Bh[r][c0 + 8] = b1;
        __syncthreads();
        f16x8 fa[4], fb[4];
#pragma unroll
        for (int t = 0; t < 4; ++t) {
            int ar = wm * 64 + t * 16 + l16;
            int br = wn * 64 + t * 16 + l16;
            fa[t] = *(const f16x8*)&Ah[ar][q * 8];
            fb[t] = *(const f16x8*)&Bh[br][q * 8];
        }
#pragma unroll
        for (int i = 0; i < 4; ++i)
#pragma unroll
            for (int j = 0; j < 4; ++j)
                acc[i][j] = __builtin_amdgcn_mfma_f32_16x16x32_f16(fa[i], fb[j], acc[i][j], 0, 0, 0);
    }
#pragma unroll
    for (int i = 0; i < 4; ++i)
#pragma unroll
        for (int j = 0; j < 4; ++j) {
            int col = wn * 64 + j * 16 + l16;
            f32x4 c = acc[i][j];
#pragma unroll
            for (int rr = 0; rr < 4; ++rr) {
                int row = wm * 64 + i * 16 + q * 4 + rr;
                Ct[row][col] = f2h(c[rr]);
            }
        }
    __syncthreads();
    int sc  = (tid & 31) * 4;
    int sr0 = tid >> 5;
#pragma unroll
    for (int p = 0; p < 16; ++p) {
        int row = p * 8 + sr0;
        *(u16x4*)(VLT + (size_t)(m0 + row) * BTOT + n0 + sc) = *(const u16x4*)&Ct[row][sc];
    }
}

// ---------------------------------------------------------------------------
// K3: S16 = f16(H . E^T) — f16, 256x256 tile, BK=64, stride-72 dbuf LDS
//   (147 KB), NOW 1024 threads = 16 waves (4Mx4N, 64x64/wave): 4 waves/SIMD
//   for latency hiding (R10 had 8 waves -> 2/SIMD, latency-bound at 24% mfma).
// ---------------------------------------------------------------------------
#define SC_NT 8
#define SC_PLANE (256 * 72)
#define SC_BUF_SH (2 * SC_PLANE)
#define SC_LDS_BYTES (2 * SC_BUF_SH * 2)   // 147456

__global__ __launch_bounds__(1024, 4) void k_scores256(const ushort_t* __restrict__ Hf,
                                                       const ushort_t* __restrict__ Ef,
                                                       ushort_t* __restrict__ S16) {
    extern __shared__ ushort_t smw[];
    int tid  = threadIdx.x;
    int wg   = blockIdx.x;          // 0..511
    int b    = wg & 7;              // XCD q -> batch q
    int rank = wg >> 3;             // 0..63 -> 8x8 tile grid in 4x4 sub-blocks
    int st   = rank >> 4;
    int r2   = rank & 15;
    int m0 = ((((st & 1) << 2) | (r2 & 3))) * 256;
    int n0 = ((((st >> 1) << 2) | (r2 >> 2))) * 256;

    // staging: g=0 (512 thr) -> H rows m0.., g=1 -> E rows n0..
    // 2 threads/row, each covers 32 shorts (4 chunks of 8) of the 64-short row
    int g = tid >> 9;
    int u = tid & 511;
    int srow = u >> 1;              // 0..255
    int scol = (u & 1) * 32;        // 0 or 32
    const ushort_t* gsrc = g ? Ef : Hf;
    int panel0 = g ? n0 : m0;
    const ushort_t* gbase = gsrc + (size_t)(b * TSEQ + panel0 + srow) * DIM + scol;
    int ldst = g * SC_PLANE + srow * 72 + scol;

    int wave = tid >> 6, lane = tid & 63;   // wave 0..15
    int wm = wave >> 2, wn = wave & 3;      // 4M x 4N, 64x64 per wave
    int l32 = lane & 31, kh = lane >> 5;
    int aoff[2], boff[2];
#pragma unroll
    for (int mt = 0; mt < 2; ++mt) aoff[mt] = (wm * 64 + mt * 32 + l32) * 72 + kh * 8;
#pragma unroll
    for (int nt = 0; nt < 2; ++nt) boff[nt] = SC_PLANE + (wn * 64 + nt * 32 + l32) * 72 + kh * 8;

    f32x16 acc[2][2];
#pragma unroll
    for (int i = 0; i < 2; ++i)
#pragma unroll
        for (int j = 0; j < 2; ++j)
#pragma unroll
            for (int t = 0; t < 16; ++t) acc[i][j][t] = 0.f;

    u16x8 st8[4];
#pragma unroll
    for (int c = 0; c < 4; ++c) st8[c] = *(const u16x8*)(gbase + c * 8);
#pragma unroll
    for (int c = 0; c < 4; ++c) *(u16x8*)&smw[ldst + c * 8] = st8[c];
    __syncthreads();

    for (int t = 0; t < SC_NT; ++t) {
        int cur = (t & 1) * SC_BUF_SH;
        if (t + 1 < SC_NT) {
            int k0n = (t + 1) * 64;
#pragma unroll
            for (int c = 0; c < 4; ++c)
                st8[c] = *(const u16x8*)(gbase + k0n + c * 8);
        }
#pragma unroll
        for (int kc = 0; kc < 4; ++kc) {
            f16x8 fa[2], fb[2];
#pragma unroll
            for (int mt = 0; mt < 2; ++mt)
                fa[mt] = *(const f16x8*)&smw[cur + aoff[mt] + kc * 16];
#pragma unroll
            for (int nt = 0; nt < 2; ++nt)
                fb[nt] = *(const f16x8*)&smw[cur + boff[nt] + kc * 16];
#pragma unroll
            for (int mt = 0; mt < 2; ++mt)
#pragma unroll
                for (int nt = 0; nt < 2; ++nt)
                    acc[mt][nt] = __builtin_amdgcn_mfma_f32_32x32x16_f16(fa[mt], fb[nt], acc[mt][nt], 0, 0, 0);
        }
        if (t + 1 < SC_NT) {
            int nxt = ((t + 1) & 1) * SC_BUF_SH;
#pragma unroll
            for (int c = 0; c < 4; ++c)
                *(u16x8*)&smw[nxt + ldst + c * 8] = st8[c];
        }
        __syncthreads();
    }

    ushort_t* Sout = S16 + (size_t)b * TSEQ * TSEQ;
#pragma unroll
    for (int mt = 0; mt < 2; ++mt)
#pragma unroll
        for (int nt = 0; nt < 2; ++nt) {
            int col = n0 + wn * 64 + nt * 32 + l32;
            f32x16 c = acc[mt][nt];
#pragma unroll
            for (int rr = 0; rr < 16; ++rr) {
                int row = m0 + wm * 64 + mt * 32 + (rr & 3) + 8 * (rr >> 2) + 4 * kh;
                Sout[(size_t)row * TSEQ + col] = f2h(c[rr]);
            }
        }
}

// ---------------------------------------------------------------------------
// K4: softexp on f16 S in place: row max, P = f16(exp(s-m)), linv = 1/sum
// ---------------------------------------------------------------------------
__global__ __launch_bounds__(256) void k_softexp(ushort_t* __restrict__ S16,
                                                 float* __restrict__ linv) {
    int row = blockIdx.x;
    int tid = threadIdx.x;
    ushort_t* r = S16 + (size_t)row * TSEQ;
    u16x8 v8 = *(const u16x8*)(r + tid * 8);
    float vv[8];
#pragma unroll
    for (int i = 0; i < 8; ++i) vv[i] = h2f(v8[i]);
    float mx = vv[0];
#pragma unroll
    for (int i = 1; i < 8; ++i) mx = fmaxf(mx, vv[i]);
#pragma unroll
    for (int off = 32; off > 0; off >>= 1) mx = fmaxf(mx, __shfl_xor(mx, off));
    __shared__ float sm[4];
    __shared__ float sl[4];
    if ((tid & 63) == 0) sm[tid >> 6] = mx;
    __syncthreads();
    mx = fmaxf(fmaxf(sm[0], sm[1]), fmaxf(sm[2], sm[3]));
    float s = 0.f;
    u16x8 p;
#pragma unroll
    for (int i = 0; i < 8; ++i) {
        float e = __expf(vv[i] - mx);
        s += e;
        p[i] = f2h(e);
    }
    *(u16x8*)(r + tid * 8) = p;
#pragma unroll
    for (int off = 32; off > 0; off >>= 1) s += __shfl_xor(s, off);
    if ((tid & 63) == 0) sl[tid >> 6] = s;
    __syncthreads();
    if (tid == 0) linv[row] = 1.f / (sl[0] + sl[1] + sl[2] + sl[3]);
}

// ---------------------------------------------------------------------------
// K5: PV — 256-tile 8-wave template, f16 MFMA, BK=64 (R10 version)
// ---------------------------------------------------------------------------
#define PV_NT 32
#define PV_A_SH (256 * 72)
#define PV_B_SH (128 * 72)
#define PV_BUF_SH (PV_A_SH + PV_B_SH)        // 27648 shorts
#define PV_LDS_BYTES (2 * PV_BUF_SH * 2)     // 110592 bytes

__global__ __launch_bounds__(512, 2) void k_pv256(const ushort_t* __restrict__ P16,
                                                  const ushort_t* __restrict__ VLT,
                                                  const float* __restrict__ linv,
                                                  const float* __restrict__ lin_b,
                                                  float* __restrict__ accg) {
    extern __shared__ ushort_t smw[];
    __shared__ float linv_s[256], bias_s[128];
    int tid  = threadIdx.x;
    int wg   = blockIdx.x;           // 0..255
    int b    = wg & 7;               // XCD q -> batch q
    int rank = wg >> 3;              // 0..31
    int m0 = (rank >> 2) * 256;      // i tile (8)
    int n0 = (rank & 3) * 128;       // d tile (4, fastest)
    if (tid < 256) linv_s[tid] = linv[b * TSEQ + m0 + tid];
    else if (tid < 384) bias_s[tid - 256] = lin_b[n0 + tid - 256];

    int srow = tid >> 3;             // 0..63
    int scol = (tid & 7) * 8;
    const ushort_t* gA = P16 + (size_t)(b * TSEQ + m0 + srow) * TSEQ + scol;
    const ushort_t* gB = VLT + (size_t)(n0 + srow) * BTOT + b * TSEQ + scol;
    int wA0 = srow * 72 + scol;
    int wB0 = PV_A_SH + srow * 72 + scol;

    int wave = tid >> 6, lane = tid & 63;
    int wm = wave >> 1, wn = wave & 1;
    int l32 = lane & 31, kh = lane >> 5;
    int aoff[2], boff[2];
#pragma unroll
    for (int mt = 0; mt < 2; ++mt) aoff[mt] = (wm * 64 + mt * 32 + l32) * 72 + kh * 8;
#pragma unroll
    for (int nt = 0; nt < 2; ++nt) boff[nt] = PV_A_SH + (wn * 64 + nt * 32 + l32) * 72 + kh * 8;

    f32x16 acc[2][2];
#pragma unroll
    for (int i = 0; i < 2; ++i)
#pragma unroll
        for (int j = 0; j < 2; ++j)
#pragma unroll
            for (int t = 0; t < 16; ++t) acc[i][j][t] = 0.f;

    u16x8 st8[6];
#pragma unroll
    for (int c = 0; c < 4; ++c) st8[c] = *(const u16x8*)(gA + (size_t)(c * 64) * TSEQ);
#pragma unroll
    for (int c = 0; c < 2; ++c) st8[4 + c] = *(const u16x8*)(gB + (size_t)(c * 64) * BTOT);
#pragma unroll
    for (int c = 0; c < 4; ++c) *(u16x8*)&smw[wA0 + c * 64 * 72] = st8[c];
#pragma unroll
    for (int c = 0; c < 2; ++c) *(u16x8*)&smw[wB0 + c * 64 * 72] = st8[4 + c];
    __syncthreads();

    for (int t = 0; t < PV_NT; ++t) {
        int cur = (t & 1) * PV_BUF_SH;
        if (t + 1 < PV_NT) {
            int k0n = (t + 1) * 64;
#pragma unroll
            for (int c = 0; c < 4; ++c)
                st8[c] = *(const u16x8*)(gA + (size_t)(c * 64) * TSEQ + k0n);
#pragma unroll
            for (int c = 0; c < 2; ++c)
                st8[4 + c] = *(const u16x8*)(gB + (size_t)(c * 64) * BTOT + k0n);
        }
#pragma unroll
        for (int kc = 0; kc < 4; ++kc) {
            int ka = kc * 16;
            f16x8 fa[2], fb[2];
#pragma unroll
            for (int mt = 0; mt < 2; ++mt) fa[mt] = *(const f16x8*)&smw[cur + aoff[mt] + ka];
#pragma unroll
            for (int nt = 0; nt < 2; ++nt) fb[nt] = *(const f16x8*)&smw[cur + boff[nt] + ka];
#pragma unroll
            for (int mt = 0; mt < 2; ++mt)
#pragma unroll
                for (int nt = 0; nt < 2; ++nt)
                    acc[mt][nt] = __builtin_amdgcn_mfma_f32_32x32x16_f16(fa[mt], fb[nt], acc[mt][nt], 0, 0, 0);
        }
        if (t + 1 < PV_NT) {
            int nxt = ((t + 1) & 1) * PV_BUF_SH;
#pragma unroll
            for (int c = 0; c < 4; ++c) *(u16x8*)&smw[nxt + wA0 + c * 64 * 72] = st8[c];
#pragma unroll
            for (int c = 0; c < 2; ++c) *(u16x8*)&smw[nxt + wB0 + c * 64 * 72] = st8[4 + c];
        }
        __syncthreads();
    }

    float dsum[2] = {0.f, 0.f};
#pragma unroll
    for (int mt = 0; mt < 2; ++mt)
#pragma unroll
        for (int nt = 0; nt < 2; ++nt) {
            f32x16 c = acc[mt][nt];
            float bias = bias_s[wn * 64 + nt * 32 + l32];
#pragma unroll
            for (int rr = 0; rr < 16; ++rr) {
                int row = wm * 64 + mt * 32 + (rr & 3) + 8 * (rr >> 2) + 4 * kh;
                float v = fmaf(c[rr], linv_s[row], bias);
                dsum[nt] += fmaxf(v, 0.f);
            }
        }
#pragma unroll
    for (int nt = 0; nt < 2; ++nt) {
        float v = dsum[nt];
        v += __shfl_xor(v, 32);
        if (kh == 0) atomicAdd(&accg[b * DIM + n0 + wn * 64 + nt * 32 + l32], v);
    }
}

// ---------------------------------------------------------------------------
// K6: out[b] = sigmoid((accg[b]/T) . clf_w + clf_b)
// ---------------------------------------------------------------------------
__global__ void k_final(const float* __restrict__ accg,
                        const float* __restrict__ clf_w,
                        const float* __restrict__ clf_b,
                        float* __restrict__ out) {
    int tid  = threadIdx.x;
    int b    = tid >> 6;
    int lane = tid & 63;
    float s = 0.f;
    for (int d = lane; d < DIM; d += 64) s = fmaf(accg[b * DIM + d], clf_w[d], s);
#pragma unroll
    for (int off = 32; off > 0; off >>= 1) s += __shfl_xor(s, off);
    if (lane == 0) {
        float z = s * (1.0f / TSEQ) + clf_b[0];
        out[b] = 1.f / (1.f + __expf(-z));
    }
}

// ---------------------------------------------------------------------------
extern "C" void kernel_launch(void* const* d_in, const int* in_sizes, int n_in,
                              void* d_out, int out_size, void* d_ws, size_t ws_size,
                              hipStream_t stream) {
    const int*   x     = (const int*)d_in[0];
    const float* embed = (const float*)d_in[1];
    const float* Wq    = (const float*)d_in[2];
    const float* Wk    = (const float*)d_in[3];
    const float* Wv    = (const float*)d_in[4];
    const float* lin_w = (const float*)d_in[5];
    const float* lin_b = (const float*)d_in[6];
    const float* clf_w = (const float*)d_in[7];
    const float* clf_b = (const float*)d_in[8];
    float* out = (float*)d_out;

    char* wsb = (char*)d_ws;
    ushort_t* S16 = (ushort_t*)wsb;                          // 67 MB f16 scores / P in place
    char* p = wsb + (size_t)NB * TSEQ * TSEQ * 4;
    ushort_t* Ef  = (ushort_t*)p;
    ushort_t* Hf  = Ef  + (size_t)BTOT * DIM;
    ushort_t* VLT = Hf  + (size_t)BTOT * DIM;
    ushort_t* Gtf = VLT + (size_t)DIM * BTOT;
    ushort_t* Mf  = Gtf + (size_t)DIM * DIM;
    float* linv = (float*)(Mf + (size_t)DIM * DIM);
    float* accg = linv + BTOT;

    static bool s_attr_done = false;
    if (!s_attr_done) {
        hipFuncSetAttribute((const void*)k_scores256,
                            hipFuncAttributeMaxDynamicSharedMemorySize, SC_LDS_BYTES);
        hipFuncSetAttribute((const void*)k_proj_h256,
                            hipFuncAttributeMaxDynamicSharedMemorySize, PH_LDS_BYTES);
        hipFuncSetAttribute((const void*)k_pv256,
                            hipFuncAttributeMaxDynamicSharedMemorySize, PV_LDS_BYTES);
        s_attr_done = true;
    }

    hipMemsetAsync(accg, 0, NB * DIM * sizeof(float), stream);
    k_split_embed<<<BTOT * 64 / 256, 256, 0, stream>>>(x, embed, Ef);
    k_wgemm<<<dim3(16, 16, 2), 256, 0, stream>>>(Wq, Wk, lin_w, Wv, Gtf, Mf);
    k_proj_h256<<<256, 512, PH_LDS_BYTES, stream>>>(Ef, Gtf, Hf);
    k_proj_vlt<<<dim3(4, 128), 256, 0, stream>>>(Mf, Ef, VLT);
    k_scores256<<<512, 1024, SC_LDS_BYTES, stream>>>(Hf, Ef, S16);
    k_softexp<<<BTOT, 256, 0, stream>>>(S16, linv);
    k_pv256<<<256, 512, PV_LDS_BYTES, stream>>>(S16, VLT, linv, lin_b, accg);
    k_final<<<1, 512, 0, stream>>>(accg, clf_w, clf_b, out);
}